// Round 5
// baseline (52.413 us; speedup 1.0000x reference)
//
#include <hip/hip_runtime.h>
#include <hip/hip_bf16.h>

typedef __bf16 bf16x8 __attribute__((ext_vector_type(8)));
typedef float f32x4 __attribute__((ext_vector_type(4)));
typedef unsigned short us8 __attribute__((ext_vector_type(8)));

#define MFMA16 __builtin_amdgcn_mfma_f32_16x16x32_bf16

__device__ __forceinline__ unsigned short f2bf(float f) {
    unsigned int u = __float_as_uint(f);
    u += 0x7fffu + ((u >> 16) & 1u);   // round-to-nearest-even
    return (unsigned short)(u >> 16);
}

__device__ __forceinline__ void gload_lds16(const void* g, void* l) {
    __builtin_amdgcn_global_load_lds(
        (const __attribute__((address_space(1))) unsigned int*)g,
        (__attribute__((address_space(3))) unsigned int*)l, 16, 0, 0);
}

// ============ Pass 1 (fused): x,h -> packed bf16 ; weights -> packed bf16 ====
// Packed frag block (mb,kb) = 1024 B; elem (m,k): mb=m>>4, r=m&15, kb=k>>5,
// kk=k&31, lane=(kk>>3)*16+r, byte=((mb*16+kb)*64+lane)*16+(kk&7)*2.
__global__ void cvt_all_kernel(const float* __restrict__ x, const float* __restrict__ h,
                               unsigned short* __restrict__ XP, unsigned short* __restrict__ HP,
                               const float* __restrict__ W0, const float* __restrict__ W1,
                               const float* __restrict__ W2, const float* __restrict__ W3,
                               const float* __restrict__ W4, const float* __restrict__ W5,
                               unsigned short* __restrict__ WP) {
    if (blockIdx.x < 4096) {                         // x,h path
        int c = blockIdx.x * 256 + threadIdx.x;      // 0 .. 2^20-1
        const float* src = (c >> 19) ? h : x;
        unsigned short* dst = (c >> 19) ? HP : XP;
        int c2 = c & 524287;
        int mb = c2 >> 10, kb = (c2 >> 6) & 15, lane = c2 & 63;
        int r = lane & 15, ko = lane >> 4;
        const float* p = src + (size_t)(mb * 16 + r) * 512 + kb * 32 + ko * 8;
        float4 v0 = *(const float4*)p;
        float4 v1 = *(const float4*)(p + 4);
        us8 o = { f2bf(v0.x), f2bf(v0.y), f2bf(v0.z), f2bf(v0.w),
                  f2bf(v1.x), f2bf(v1.y), f2bf(v1.z), f2bf(v1.w) };
        *(us8*)(dst + (size_t)c2 * 8) = o;
    } else {                                          // weights path
        int c = (blockIdx.x - 4096) * 256 + threadIdx.x;   // 0 .. 196607
        int w = c >> 15;
        const float* Wsrc;
        switch (w) {
            case 0: Wsrc = W0; break;
            case 1: Wsrc = W1; break;
            case 2: Wsrc = W2; break;
            case 3: Wsrc = W3; break;
            case 4: Wsrc = W4; break;
            default: Wsrc = W5; break;
        }
        int c2 = c & 32767;
        int nb = c2 >> 10, kb = (c2 >> 6) & 15, lane = c2 & 63;
        int cc = lane & 15, ko = lane >> 4;
        int kbase = kb * 32 + ko * 8;
        us8 o;
#pragma unroll
        for (int e = 0; e < 8; ++e)
            o[e] = f2bf(Wsrc[(size_t)(kbase + e) * 512 + nb * 16 + cc]);
        *(us8*)(WP + (size_t)c * 8) = o;
    }
}

// ============ Pass 2: fused 6-GEMM + AUGRU epilogue ============
// Block: 512 threads = 8 waves (4 wave-rows x 2 wave-cols); tile 256r x 32c.
// Wave: 64 rows x 16 cols; acc = 4mf x 4sets x f32x4 = 64 VGPR.
// B: K=128 chunk of all 6 weight panels staged in LDS (48 KB) via
//    global_load_lds; then 4 BARRIER-FREE K-steps (ds_read + MFMA + A-loads).
// A: global->reg per step (L2-local via XCD swizzle). 8 syncthreads total.
__global__ __launch_bounds__(512, 4) void augru_mm(
    const unsigned short* __restrict__ XP,
    const unsigned short* __restrict__ HP,
    const unsigned short* __restrict__ WP,   // frag f = w*512 + nb*16 + kb, byte f*1024+lane*16
    const float* __restrict__ b_r, const float* __restrict__ b_u, const float* __restrict__ b_h,
    const float* __restrict__ att, const float* __restrict__ h32,
    float* __restrict__ out) {
    __shared__ unsigned char sB[48 * 1024];   // [s 0..5][nf 0..1][kbi 0..3][1KB]

    const int t = threadIdx.x;
    const int wv = t >> 6, lane = t & 63;
    const int laneoff = lane * 16;

    // bijective XCD swizzle: XCD x owns W in [x*64,(x+1)*64) -> 4 m-panels, L2-local A
    const int bid = blockIdx.x;                 // 0..511
    const int W = (bid & 7) * 64 + (bid >> 3);
    const int mblk = W >> 4, nblk = W & 15;     // 32 m-panels(256r) x 16 n-panels(32c)
    const int wr = wv >> 1, wc = wv & 1;

    f32x4 accR[4] = {}, accU[4] = {}, accXH[4] = {}, accHH[4] = {};

    const unsigned char* XPb = (const unsigned char*)XP;
    const unsigned char* HPb = (const unsigned char*)HP;
    const unsigned char* WPb = (const unsigned char*)WP;

    // A frag uniform byte offsets per mf (mb = mblk*16 + wr*4 + mf)
    size_t aoff[4];
#pragma unroll
    for (int mf = 0; mf < 4; ++mf)
        aoff[mf] = ((size_t)((mblk * 16 + wr * 4 + mf) * 16) << 10) + laneoff;

    // staging map: thread handles frag ids fid = wv + i*8, i=0..5 (48 frags)
    // fid -> s = fid>>3, nf = (fid>>2)&1, kbi = fid&3
    const unsigned char* wsrc[6];
    unsigned sdst[6];
#pragma unroll
    for (int i = 0; i < 6; ++i) {
        int fid = wv + i * 8;
        int s = fid >> 3, nf = (fid >> 2) & 1, kbi = fid & 3;
        wsrc[i] = WPb + ((size_t)(s * 512 + (nblk * 2 + nf) * 16 + kbi) << 10) + laneoff;
        sdst[i] = (unsigned)fid << 10;          // wave-uniform; HW adds lane*16
    }

#pragma unroll
    for (int c = 0; c < 4; ++c) {               // 4 chunks of K=128
        __syncthreads();                        // all waves done reading prev chunk
#pragma unroll
        for (int i = 0; i < 6; ++i)
            gload_lds16(wsrc[i] + ((size_t)c << 12), &sB[sdst[i]]);
        __syncthreads();                        // drain DMAs (vmcnt0) + publish

#pragma unroll
        for (int kbi = 0; kbi < 4; ++kbi) {     // barrier-free steps
            const int kb = c * 4 + kbi;
            const size_t koff = (size_t)kb << 10;
            bf16x8 ax[4], ah[4];
#pragma unroll
            for (int mf = 0; mf < 4; ++mf) ax[mf] = *(const bf16x8*)(XPb + aoff[mf] + koff);
            const unsigned rb = (unsigned)((wc * 4 + kbi) << 10) + laneoff;
            bf16x8 b0 = *(const bf16x8*)&sB[0 * 8192 + rb];
            bf16x8 b2 = *(const bf16x8*)&sB[2 * 8192 + rb];
            bf16x8 b4 = *(const bf16x8*)&sB[4 * 8192 + rb];
#pragma unroll
            for (int mf = 0; mf < 4; ++mf) ah[mf] = *(const bf16x8*)(HPb + aoff[mf] + koff);
            __builtin_amdgcn_s_setprio(1);
#pragma unroll
            for (int mf = 0; mf < 4; ++mf) {
                accR[mf]  = MFMA16(ax[mf], b0, accR[mf], 0, 0, 0);
                accU[mf]  = MFMA16(ax[mf], b2, accU[mf], 0, 0, 0);
                accXH[mf] = MFMA16(ax[mf], b4, accXH[mf], 0, 0, 0);
            }
            __builtin_amdgcn_s_setprio(0);
            bf16x8 b1 = *(const bf16x8*)&sB[1 * 8192 + rb];
            bf16x8 b3 = *(const bf16x8*)&sB[3 * 8192 + rb];
            bf16x8 b5 = *(const bf16x8*)&sB[5 * 8192 + rb];
            __builtin_amdgcn_s_setprio(1);
#pragma unroll
            for (int mf = 0; mf < 4; ++mf) {
                accR[mf]  = MFMA16(ah[mf], b1, accR[mf], 0, 0, 0);
                accU[mf]  = MFMA16(ah[mf], b3, accU[mf], 0, 0, 0);
                accHH[mf] = MFMA16(ah[mf], b5, accHH[mf], 0, 0, 0);
            }
            __builtin_amdgcn_s_setprio(0);
        }
    }

    // epilogue: C/D layout col=lane&15, row=(lane>>4)*4+reg  [m89-verified]
    const int lr = lane & 15, lg = lane >> 4;
    const int col = nblk * 32 + wc * 16 + lr;
    const float br = b_r[col], bu = b_u[col], bh = b_h[col];
#pragma unroll
    for (int mf = 0; mf < 4; ++mf) {
        const int rowb = mblk * 256 + wr * 64 + mf * 16 + lg * 4;
#pragma unroll
        for (int q = 0; q < 4; ++q) {
            const int row = rowb + q;
            float r = 1.f / (1.f + __expf(-(accR[mf][q] + br)));
            float u = 1.f / (1.f + __expf(-(accU[mf][q] + bu)));
            float ph = accXH[mf][q] + bh + r * accHH[mf][q];
            ph = fminf(fmaxf(ph, -15.f), 15.f);
            float e = __expf(2.f * ph);
            float cal = (e - 1.f) / (e + 1.f);
            float hv = h32[(size_t)row * 512 + col];
            float ua = att[row] * u;
            out[(size_t)row * 512 + col] = fmaf(ua, cal - hv, hv);
        }
    }
}

extern "C" void kernel_launch(void* const* d_in, const int* in_sizes, int n_in,
                              void* d_out, int out_size, void* d_ws, size_t ws_size,
                              hipStream_t stream) {
    const float* x    = (const float*)d_in[0];
    const float* h    = (const float*)d_in[1];
    const float* att  = (const float*)d_in[2];
    const float* Wx_r = (const float*)d_in[3];
    const float* b_r  = (const float*)d_in[4];
    const float* Wh_r = (const float*)d_in[5];
    const float* Wx_u = (const float*)d_in[6];
    const float* b_u  = (const float*)d_in[7];
    const float* Wh_u = (const float*)d_in[8];
    const float* Wx_h = (const float*)d_in[9];
    const float* b_h  = (const float*)d_in[10];
    const float* Wh_h = (const float*)d_in[11];
    float* out = (float*)d_out;

    unsigned short* XP = (unsigned short*)d_ws;           // 8 MiB
    unsigned short* HP = XP + 8192 * 512;                 // 8 MiB
    unsigned short* WP = HP + 8192 * 512;                 // 3 MiB

    cvt_all_kernel<<<4864, 256, 0, stream>>>(x, h, XP, HP,
        Wx_r, Wh_r, Wx_u, Wh_u, Wx_h, Wh_h, WP);
    augru_mm<<<512, 512, 0, stream>>>(XP, HP, WP, b_r, b_u, b_h, att, h, out);
}

// Round 6
// 45.944 us; speedup vs baseline: 1.1408x; 1.1408x over previous
//
#include <hip/hip_runtime.h>
#include <hip/hip_bf16.h>

typedef __bf16 bf16x8 __attribute__((ext_vector_type(8)));
typedef float f32x4 __attribute__((ext_vector_type(4)));
typedef unsigned short us8 __attribute__((ext_vector_type(8)));

#define MFMA16 __builtin_amdgcn_mfma_f32_16x16x32_bf16

__device__ __forceinline__ unsigned short f2bf(float f) {
    unsigned int u = __float_as_uint(f);
    u += 0x7fffu + ((u >> 16) & 1u);   // round-to-nearest-even
    return (unsigned short)(u >> 16);
}

__device__ __forceinline__ void gload_lds16(const void* g, void* l) {
    __builtin_amdgcn_global_load_lds(
        (const __attribute__((address_space(1))) unsigned int*)g,
        (__attribute__((address_space(3))) unsigned int*)l, 16, 0, 0);
}

// ============ Pass 1 (fused): pack A' = [x | h] along K' and B-hat panels ====
// Frag = 1024 B = 16 rows x 32 k (lane=(kk>>3)*16+row, 8 contig k per lane).
// A': frag index = mb*32 + kb'  (kb' = kb for x, 16+kb for h), mb 0..511.
// B-hat: 3 buffers (R,U,C) of [nb 0..31][kb' 0..31] frags; kb'<16 from Wx_*,
//        kb'>=16 from Wh_*.
__global__ void cvt_all_kernel(const float* __restrict__ x, const float* __restrict__ h,
                               unsigned short* __restrict__ AP,
                               const float* __restrict__ W0, const float* __restrict__ W1,
                               const float* __restrict__ W2, const float* __restrict__ W3,
                               const float* __restrict__ W4, const float* __restrict__ W5,
                               unsigned short* __restrict__ WP) {
    if (blockIdx.x < 4096) {                         // x,h -> A'
        int c = blockIdx.x * 256 + threadIdx.x;      // 0 .. 2^20-1
        int ih = c >> 19;
        const float* src = ih ? h : x;
        int c2 = c & 524287;
        int mb = c2 >> 10, kb = (c2 >> 6) & 15, lane = c2 & 63;
        int r = lane & 15, ko = lane >> 4;
        const float* p = src + (size_t)(mb * 16 + r) * 512 + kb * 32 + ko * 8;
        float4 v0 = *(const float4*)p;
        float4 v1 = *(const float4*)(p + 4);
        us8 o = { f2bf(v0.x), f2bf(v0.y), f2bf(v0.z), f2bf(v0.w),
                  f2bf(v1.x), f2bf(v1.y), f2bf(v1.z), f2bf(v1.w) };
        *((us8*)AP + ((size_t)(mb * 32 + kb + ih * 16) << 6) + lane) = o;
    } else {                                          // weights -> B-hat
        int c = (blockIdx.x - 4096) * 256 + threadIdx.x;   // 0..196607
        int s = c >> 16, c2 = c & 65535;
        int frag = c2 >> 6, lane = c2 & 63;
        int nb = frag >> 5, kbp = frag & 31;
        const float* Wsrc;
        int kb;
        if (kbp < 16) { kb = kbp;      Wsrc = (s == 0) ? W0 : (s == 1) ? W2 : W4; }
        else          { kb = kbp - 16; Wsrc = (s == 0) ? W1 : (s == 1) ? W3 : W5; }
        int cc = lane & 15, ko = lane >> 4;
        int kbase = kb * 32 + ko * 8;
        us8 o;
#pragma unroll
        for (int e = 0; e < 8; ++e)
            o[e] = f2bf(Wsrc[(size_t)(kbase + e) * 512 + nb * 16 + cc]);
        *((us8*)WP + c) = o;
    }
}

// ============ Pass 2: fused GEMM + AUGRU epilogue (m201-style schedule) =====
// Tile 256r x 64c, BK'=64, 16 steps over K'=1024. 8 waves (4M x 2N),
// wave = 64r x 32c, 3 active acc-sets/step {R,U,C(xh|hh)}.
// LDS: 2 x 56 KB (A 32 KB + B 24 KB), linear frags, gload_lds width-16.
// Per step: vmcnt(7)+bar -> ds_read+48 MFMA -> lgkm(0)+bar -> issue k+2.
__global__ __launch_bounds__(512, 2) void augru_mm(
    const unsigned short* __restrict__ AP_,
    const unsigned short* __restrict__ WP_,   // 3 x 1 MiB (R,U,C)
    const float* __restrict__ b_r, const float* __restrict__ b_u, const float* __restrict__ b_h,
    const float* __restrict__ att, const float* __restrict__ h32,
    float* __restrict__ out) {
    __shared__ unsigned char sL[2][57344];
    const unsigned char* AP  = (const unsigned char*)AP_;
    const unsigned char* WPb = (const unsigned char*)WP_;

    const int t = threadIdx.x, wv = t >> 6, lane = t & 63;
    const int laneoff = lane * 16;

    // bijective XCD swizzle: XCD x owns Wid in [32x, 32x+32) -> 4 m-panels
    const int bid = blockIdx.x;                 // 0..255
    const int Wid = (bid & 7) * 32 + (bid >> 3);
    const int mblk = Wid >> 3, nblk = Wid & 7;  // 32 m-panels x 8 n-panels
    const int wr = wv >> 1, wc = wv & 1;        // 4M x 2N wave grid

    f32x4 accR[4][2] = {}, accU[4][2] = {}, accXH[4][2] = {}, accHH[4][2] = {};

    // staging sources/dests: 7 issues/step x 512 threads x 16 B = 56 KB
    const unsigned char* gsrc[7];
    unsigned ldst[7];
#pragma unroll
    for (int i = 0; i < 4; ++i) {               // A: frags f = i*8+wv (0..31)
        int f = i * 8 + wv, mbL = f >> 1, kq = f & 1;
        gsrc[i] = AP + ((size_t)((mblk * 16 + mbL) * 32 + kq) << 10) + laneoff;
        ldst[i] = (unsigned)f << 10;
    }
#pragma unroll
    for (int i = 4; i < 7; ++i) {               // B: frags g = (i-4)*8+wv (0..23)
        int g = (i - 4) * 8 + wv, s = g >> 3, nbL = (g >> 1) & 3, kq = g & 1;
        gsrc[i] = WPb + (size_t)s * 1048576 +
                  ((size_t)((nblk * 4 + nbL) * 32 + kq) << 10) + laneoff;
        ldst[i] = 32768u + ((unsigned)g << 10);
    }

    // ds_read byte offsets (within a buffer)
    unsigned aoff[4], boff[3][2];
#pragma unroll
    for (int mf = 0; mf < 4; ++mf) aoff[mf] = (((wr * 4 + mf) * 2) << 10) + laneoff;
#pragma unroll
    for (int s = 0; s < 3; ++s)
#pragma unroll
        for (int nf = 0; nf < 2; ++nf)
            boff[s][nf] = 32768u + (((s * 4 + wc * 2 + nf) * 2) << 10) + laneoff;

#define ISSUE(kk, bufi) { _Pragma("unroll") for (int i = 0; i < 7; ++i) \
        gload_lds16(gsrc[i] + ((size_t)(kk) << 11), &sL[bufi][ldst[i]]); }

#define WAITBAR(n) asm volatile("s_waitcnt vmcnt(" #n ")\n\ts_barrier" ::: "memory");
#define RELBAR     asm volatile("s_waitcnt lgkmcnt(0)\n\ts_barrier" ::: "memory");

#define COMPUTE(bufp, ACCC) { _Pragma("unroll") for (int kq = 0; kq < 2; ++kq) { \
        bf16x8 ax[4]; \
        _Pragma("unroll") for (int mf = 0; mf < 4; ++mf) \
            ax[mf] = *(const bf16x8*)((bufp) + aoff[mf] + (kq << 10)); \
        bf16x8 bR[2], bU[2], bC[2]; \
        _Pragma("unroll") for (int nf = 0; nf < 2; ++nf) { \
            bR[nf] = *(const bf16x8*)((bufp) + boff[0][nf] + (kq << 10)); \
            bU[nf] = *(const bf16x8*)((bufp) + boff[1][nf] + (kq << 10)); \
            bC[nf] = *(const bf16x8*)((bufp) + boff[2][nf] + (kq << 10)); } \
        __builtin_amdgcn_s_setprio(1); \
        _Pragma("unroll") for (int mf = 0; mf < 4; ++mf) \
            _Pragma("unroll") for (int nf = 0; nf < 2; ++nf) { \
                accR[mf][nf] = MFMA16(ax[mf], bR[nf], accR[mf][nf], 0, 0, 0); \
                accU[mf][nf] = MFMA16(ax[mf], bU[nf], accU[mf][nf], 0, 0, 0); \
                ACCC[mf][nf] = MFMA16(ax[mf], bC[nf], ACCC[mf][nf], 0, 0, 0); } \
        __builtin_amdgcn_s_setprio(0); } }

    // prologue: 2-deep prefetch (14 loads in flight)
    ISSUE(0, 0)
    ISSUE(1, 1)

#pragma unroll 1
    for (int k = 0; k < 8; ++k) {               // x-half: C-set = xh
        unsigned char* bufp = &sL[k & 1][0];
        WAITBAR(7)
        COMPUTE(bufp, accXH)
        RELBAR
        ISSUE(k + 2, k & 1)
    }
#pragma unroll 1
    for (int k = 8; k < 14; ++k) {              // h-half: C-set = hh
        unsigned char* bufp = &sL[k & 1][0];
        WAITBAR(7)
        COMPUTE(bufp, accHH)
        RELBAR
        ISSUE(k + 2, k & 1)
    }
    {   unsigned char* bufp = &sL[0][0];        // step 14
        WAITBAR(7)
        COMPUTE(bufp, accHH)
        RELBAR }
    {   unsigned char* bufp = &sL[1][0];        // step 15
        WAITBAR(0)
        COMPUTE(bufp, accHH) }

    // epilogue: C/D layout col=lane&15, row=(lane>>4)*4+reg  [m89-verified]
    const int lr = lane & 15, lg = lane >> 4;
#pragma unroll
    for (int nf = 0; nf < 2; ++nf) {
        const int col = nblk * 64 + wc * 32 + nf * 16 + lr;
        const float br = b_r[col], bu = b_u[col], bh = b_h[col];
#pragma unroll
        for (int mf = 0; mf < 4; ++mf) {
            const int rowb = mblk * 256 + wr * 64 + mf * 16 + lg * 4;
#pragma unroll
            for (int q = 0; q < 4; ++q) {
                const int row = rowb + q;
                float r = 1.f / (1.f + __expf(-(accR[mf][nf][q] + br)));
                float u = 1.f / (1.f + __expf(-(accU[mf][nf][q] + bu)));
                float ph = accXH[mf][nf][q] + bh + r * accHH[mf][nf][q];
                ph = fminf(fmaxf(ph, -15.f), 15.f);
                float e = __expf(2.f * ph);
                float cal = (e - 1.f) / (e + 1.f);
                float hv = h32[(size_t)row * 512 + col];
                float ua = att[row] * u;
                out[(size_t)row * 512 + col] = fmaf(ua, cal - hv, hv);
            }
        }
    }
#undef ISSUE
#undef WAITBAR
#undef RELBAR
#undef COMPUTE
}

extern "C" void kernel_launch(void* const* d_in, const int* in_sizes, int n_in,
                              void* d_out, int out_size, void* d_ws, size_t ws_size,
                              hipStream_t stream) {
    const float* x    = (const float*)d_in[0];
    const float* h    = (const float*)d_in[1];
    const float* att  = (const float*)d_in[2];
    const float* Wx_r = (const float*)d_in[3];
    const float* b_r  = (const float*)d_in[4];
    const float* Wh_r = (const float*)d_in[5];
    const float* Wx_u = (const float*)d_in[6];
    const float* b_u  = (const float*)d_in[7];
    const float* Wh_u = (const float*)d_in[8];
    const float* Wx_h = (const float*)d_in[9];
    const float* b_h  = (const float*)d_in[10];
    const float* Wh_h = (const float*)d_in[11];
    float* out = (float*)d_out;

    unsigned short* AP = (unsigned short*)d_ws;   // 16 MiB packed [x|h]
    unsigned short* WP = AP + 8388608;            //  3 MiB packed B-hat (R,U,C)

    cvt_all_kernel<<<4864, 256, 0, stream>>>(x, h, AP,
        Wx_r, Wh_r, Wx_u, Wh_u, Wx_h, Wh_h, WP);
    augru_mm<<<256, 512, 0, stream>>>(AP, WP, b_r, b_u, b_h, att, h, out);
}

// Round 7
// 45.729 us; speedup vs baseline: 1.1462x; 1.0047x over previous
//
#include <hip/hip_runtime.h>
#include <hip/hip_bf16.h>

typedef __bf16 bf16x8 __attribute__((ext_vector_type(8)));
typedef float f32x4 __attribute__((ext_vector_type(4)));
typedef unsigned short us8 __attribute__((ext_vector_type(8)));

#define MFMA16 __builtin_amdgcn_mfma_f32_16x16x32_bf16

__device__ __forceinline__ unsigned short f2bf(float f) {
    unsigned int u = __float_as_uint(f);
    u += 0x7fffu + ((u >> 16) & 1u);   // round-to-nearest-even
    return (unsigned short)(u >> 16);
}

__device__ __forceinline__ void gload_lds16(const void* g, void* l) {
    __builtin_amdgcn_global_load_lds(
        (const __attribute__((address_space(1))) unsigned int*)g,
        (__attribute__((address_space(3))) unsigned int*)l, 16, 0, 0);
}

// ============ Pass 1 (fused): pack A' = [x | h] along K' and B-hat panels ====
// Frag = 1024 B = 16 rows x 32 k (lane=(kk>>3)*16+row, 8 contig k per lane).
// A': frag index = mb*32 + kb'  (kb' = kb for x, 16+kb for h), mb 0..511.
// B-hat: 3 buffers (R,U,C) of [nb 0..31][kb' 0..31] frags; kb'<16 from Wx_*,
//        kb'>=16 from Wh_*.
__global__ void cvt_all_kernel(const float* __restrict__ x, const float* __restrict__ h,
                               unsigned short* __restrict__ AP,
                               const float* __restrict__ W0, const float* __restrict__ W1,
                               const float* __restrict__ W2, const float* __restrict__ W3,
                               const float* __restrict__ W4, const float* __restrict__ W5,
                               unsigned short* __restrict__ WP) {
    if (blockIdx.x < 4096) {                         // x,h -> A'
        int c = blockIdx.x * 256 + threadIdx.x;      // 0 .. 2^20-1
        int ih = c >> 19;
        const float* src = ih ? h : x;
        int c2 = c & 524287;
        int mb = c2 >> 10, kb = (c2 >> 6) & 15, lane = c2 & 63;
        int r = lane & 15, ko = lane >> 4;
        const float* p = src + (size_t)(mb * 16 + r) * 512 + kb * 32 + ko * 8;
        float4 v0 = *(const float4*)p;
        float4 v1 = *(const float4*)(p + 4);
        us8 o = { f2bf(v0.x), f2bf(v0.y), f2bf(v0.z), f2bf(v0.w),
                  f2bf(v1.x), f2bf(v1.y), f2bf(v1.z), f2bf(v1.w) };
        *((us8*)AP + ((size_t)(mb * 32 + kb + ih * 16) << 6) + lane) = o;
    } else {                                          // weights -> B-hat
        int c = (blockIdx.x - 4096) * 256 + threadIdx.x;   // 0..196607
        int s = c >> 16, c2 = c & 65535;
        int frag = c2 >> 6, lane = c2 & 63;
        int nb = frag >> 5, kbp = frag & 31;
        const float* Wsrc;
        int kb;
        if (kbp < 16) { kb = kbp;      Wsrc = (s == 0) ? W0 : (s == 1) ? W2 : W4; }
        else          { kb = kbp - 16; Wsrc = (s == 0) ? W1 : (s == 1) ? W3 : W5; }
        int cc = lane & 15, ko = lane >> 4;
        int kbase = kb * 32 + ko * 8;
        us8 o;
#pragma unroll
        for (int e = 0; e < 8; ++e)
            o[e] = f2bf(Wsrc[(size_t)(kbase + e) * 512 + nb * 16 + cc]);
        *((us8*)WP + c) = o;
    }
}

// ============ Pass 2: fused GEMM + AUGRU epilogue — true 8-phase schedule ====
// Tile 256r x 64c, K-tile BK=64 (16 tiles over K'=1024), 8 waves (4M x 2N),
// wave = 64r x 32c. Each K-tile = 4 phases x 12 MFMA:
//   {ds_reads; s_barrier; lgkmcnt(0)+sched_barrier(0); setprio(1); 12 MFMA;
//    setprio(0); s_barrier}
// Loads for tile t+2 burst after tile t's last barrier -> vmcnt(7)+barrier:
// counted, never drained in steady state (T3+T4), 7 loads always in flight.
__global__ __launch_bounds__(512, 2) void augru_mm(
    const unsigned short* __restrict__ AP_,
    const unsigned short* __restrict__ WP_,   // 3 x 1 MiB (R,U,C)
    const float* __restrict__ b_r, const float* __restrict__ b_u, const float* __restrict__ b_h,
    const float* __restrict__ att, const float* __restrict__ h32,
    float* __restrict__ out) {
    __shared__ unsigned char sL[2][57344];
    const unsigned char* AP  = (const unsigned char*)AP_;
    const unsigned char* WPb = (const unsigned char*)WP_;

    const int t = threadIdx.x, wv = t >> 6, lane = t & 63;
    const int laneoff = lane * 16;

    // bijective XCD swizzle: XCD x owns Wid in [32x, 32x+32) -> 4 m-panels
    const int bid = blockIdx.x;                 // 0..255
    const int Wid = (bid & 7) * 32 + (bid >> 3);
    const int mblk = Wid >> 3, nblk = Wid & 7;  // 32 m-panels x 8 n-panels
    const int wr = wv >> 1, wc = wv & 1;        // 4M x 2N wave grid

    f32x4 accR[4][2] = {}, accU[4][2] = {}, accXH[4][2] = {}, accHH[4][2] = {};

    // staging: 7 gloads/wave/K-tile (A 4, B 3), 56 KB per buffer
    const unsigned char* gsrc[7];
    unsigned ldst[7];
#pragma unroll
    for (int i = 0; i < 4; ++i) {               // A: frags f = i*8+wv (0..31)
        int f = i * 8 + wv, mbL = f >> 1, kq = f & 1;
        gsrc[i] = AP + ((size_t)((mblk * 16 + mbL) * 32 + kq) << 10) + laneoff;
        ldst[i] = (unsigned)f << 10;
    }
#pragma unroll
    for (int i = 4; i < 7; ++i) {               // B: frags g = (i-4)*8+wv (0..23)
        int g = (i - 4) * 8 + wv, s = g >> 3, nbL = (g >> 1) & 3, kq = g & 1;
        gsrc[i] = WPb + (size_t)s * 1048576 +
                  ((size_t)((nblk * 4 + nbL) * 32 + kq) << 10) + laneoff;
        ldst[i] = 32768u + ((unsigned)g << 10);
    }

    // ds_read byte offsets within a buffer (kq0; kq1 = +1024)
    unsigned aoff[4], boff[3][2];
#pragma unroll
    for (int mf = 0; mf < 4; ++mf) aoff[mf] = (((wr * 4 + mf) * 2) << 10) + laneoff;
#pragma unroll
    for (int s = 0; s < 3; ++s)
#pragma unroll
        for (int nf = 0; nf < 2; ++nf)
            boff[s][nf] = 32768u + (((s * 4 + wc * 2 + nf) * 2) << 10) + laneoff;

#define ISSUE(TT, BI) { _Pragma("unroll") for (int i = 0; i < 7; ++i) \
        gload_lds16(gsrc[i] + ((size_t)(TT) << 11), &sL[BI][ldst[i]]); }

#define VM7BAR asm volatile("s_waitcnt vmcnt(7)" ::: "memory"); \
               __builtin_amdgcn_s_barrier();
#define VM0BAR asm volatile("s_waitcnt vmcnt(0)" ::: "memory"); \
               __builtin_amdgcn_s_barrier();

#define LDA(mf, kq) (*(const bf16x8*)(bufp + aoff[mf] + ((kq) << 10)))
#define LDB(s, nf, kq) (*(const bf16x8*)(bufp + boff[s][nf] + ((kq) << 10)))

#define MM6(av, mf, nf, ACCC) \
    accR[mf][nf] = MFMA16(av, bRr[nf], accR[mf][nf], 0, 0, 0); \
    accU[mf][nf] = MFMA16(av, bUr[nf], accU[mf][nf], 0, 0, 0); \
    ACCC[mf][nf] = MFMA16(av, bCr[nf], ACCC[mf][nf], 0, 0, 0);

#define PH_MID \
    __builtin_amdgcn_s_barrier(); \
    asm volatile("s_waitcnt lgkmcnt(0)" ::: "memory"); \
    __builtin_amdgcn_sched_barrier(0); \
    __builtin_amdgcn_s_setprio(1);

#define PH_END \
    __builtin_amdgcn_s_setprio(0); \
    __builtin_amdgcn_s_barrier();

#define DO_TILE(BUFP, ACCC) { \
    const unsigned char* bufp = (BUFP); \
    bf16x8 a0, a1, bRr[2], bUr[2], bCr[2]; \
    /* P0: kq0, mf0-1 (8 ds_reads) */ \
    a0 = LDA(0, 0); a1 = LDA(1, 0); \
    bRr[0] = LDB(0, 0, 0); bRr[1] = LDB(0, 1, 0); \
    bUr[0] = LDB(1, 0, 0); bUr[1] = LDB(1, 1, 0); \
    bCr[0] = LDB(2, 0, 0); bCr[1] = LDB(2, 1, 0); \
    PH_MID MM6(a0, 0, 0, ACCC) MM6(a0, 0, 1, ACCC) \
           MM6(a1, 1, 0, ACCC) MM6(a1, 1, 1, ACCC) PH_END \
    /* P1: kq0, mf2-3 (2 ds_reads, B regs reused) */ \
    a0 = LDA(2, 0); a1 = LDA(3, 0); \
    PH_MID MM6(a0, 2, 0, ACCC) MM6(a0, 2, 1, ACCC) \
           MM6(a1, 3, 0, ACCC) MM6(a1, 3, 1, ACCC) PH_END \
    /* P2: kq1, mf0-1 (8 ds_reads) */ \
    a0 = LDA(0, 1); a1 = LDA(1, 1); \
    bRr[0] = LDB(0, 0, 1); bRr[1] = LDB(0, 1, 1); \
    bUr[0] = LDB(1, 0, 1); bUr[1] = LDB(1, 1, 1); \
    bCr[0] = LDB(2, 0, 1); bCr[1] = LDB(2, 1, 1); \
    PH_MID MM6(a0, 0, 0, ACCC) MM6(a0, 0, 1, ACCC) \
           MM6(a1, 1, 0, ACCC) MM6(a1, 1, 1, ACCC) PH_END \
    /* P3: kq1, mf2-3 (2 ds_reads) */ \
    a0 = LDA(2, 1); a1 = LDA(3, 1); \
    PH_MID MM6(a0, 2, 0, ACCC) MM6(a0, 2, 1, ACCC) \
           MM6(a1, 3, 0, ACCC) MM6(a1, 3, 1, ACCC) PH_END \
}

    // prologue: tiles 0,1 in flight; wait tile0 (7 of tile1 stay in flight)
    ISSUE(0, 0)
    ISSUE(1, 1)
    VM7BAR

#pragma unroll 1
    for (int tt = 0; tt < 8; ++tt) {            // x-half: C-set = xh
        DO_TILE(&sL[tt & 1][0], accXH)
        ISSUE(tt + 2, tt & 1)
        VM7BAR
    }
#pragma unroll 1
    for (int tt = 8; tt < 14; ++tt) {           // h-half: C-set = hh
        DO_TILE(&sL[tt & 1][0], accHH)
        ISSUE(tt + 2, tt & 1)
        VM7BAR
    }
    DO_TILE(&sL[0][0], accHH)                   // tile 14
    VM0BAR                                      // tail drain (tile 15's loads)
    DO_TILE(&sL[1][0], accHH)                   // tile 15

    // epilogue: C/D layout col=lane&15, row=(lane>>4)*4+reg  [m89-verified]
    const int lr = lane & 15, lg = lane >> 4;
#pragma unroll
    for (int nf = 0; nf < 2; ++nf) {
        const int col = nblk * 64 + wc * 32 + nf * 16 + lr;
        const float br = b_r[col], bu = b_u[col], bh = b_h[col];
#pragma unroll
        for (int mf = 0; mf < 4; ++mf) {
            const int rowb = mblk * 256 + wr * 64 + mf * 16 + lg * 4;
#pragma unroll
            for (int q = 0; q < 4; ++q) {
                const int row = rowb + q;
                float r = 1.f / (1.f + __expf(-(accR[mf][nf][q] + br)));
                float u = 1.f / (1.f + __expf(-(accU[mf][nf][q] + bu)));
                float ph = accXH[mf][nf][q] + bh + r * accHH[mf][nf][q];
                ph = fminf(fmaxf(ph, -15.f), 15.f);
                float e = __expf(2.f * ph);
                float cal = (e - 1.f) / (e + 1.f);
                float hv = h32[(size_t)row * 512 + col];
                float ua = att[row] * u;
                out[(size_t)row * 512 + col] = fmaf(ua, cal - hv, hv);
            }
        }
    }
#undef ISSUE
#undef VM7BAR
#undef VM0BAR
#undef LDA
#undef LDB
#undef MM6
#undef PH_MID
#undef PH_END
#undef DO_TILE
}

extern "C" void kernel_launch(void* const* d_in, const int* in_sizes, int n_in,
                              void* d_out, int out_size, void* d_ws, size_t ws_size,
                              hipStream_t stream) {
    const float* x    = (const float*)d_in[0];
    const float* h    = (const float*)d_in[1];
    const float* att  = (const float*)d_in[2];
    const float* Wx_r = (const float*)d_in[3];
    const float* b_r  = (const float*)d_in[4];
    const float* Wh_r = (const float*)d_in[5];
    const float* Wx_u = (const float*)d_in[6];
    const float* b_u  = (const float*)d_in[7];
    const float* Wh_u = (const float*)d_in[8];
    const float* Wx_h = (const float*)d_in[9];
    const float* b_h  = (const float*)d_in[10];
    const float* Wh_h = (const float*)d_in[11];
    float* out = (float*)d_out;

    unsigned short* AP = (unsigned short*)d_ws;   // 16 MiB packed [x|h]
    unsigned short* WP = AP + 8388608;            //  3 MiB packed B-hat (R,U,C)

    cvt_all_kernel<<<4864, 256, 0, stream>>>(x, h, AP,
        Wx_r, Wh_r, Wx_u, Wh_u, Wx_h, Wh_h, WP);
    augru_mm<<<256, 512, 0, stream>>>(AP, WP, b_r, b_u, b_h, att, h, out);
}